// Round 17
// baseline (231.205 us; speedup 1.0000x reference)
//
#include <hip/hip_runtime.h>
#include <hip/hip_bf16.h>
#include <cstdint>

typedef short bf16x8 __attribute__((ext_vector_type(8)));
typedef float f32x4 __attribute__((ext_vector_type(4)));
typedef uint uintx4 __attribute__((ext_vector_type(4)));
typedef float floatx4 __attribute__((ext_vector_type(4)));

// ---------------- bf16 helpers ----------------

__device__ inline float blo(uint u) { return __uint_as_float(u << 16); }
__device__ inline float bhi(uint u) { return __uint_as_float(u & 0xffff0000u); }
__device__ inline ushort f2bu(float x) {
    __hip_bfloat16 h = __float2bfloat16(x);
    return *reinterpret_cast<ushort*>(&h);
}
__device__ inline uint fpack2(float x, float y) {
    return (uint)f2bu(x) | ((uint)f2bu(y) << 16);
}

// 8 channels from one uint4 into acc[0..7]
#define ACC8(v)                                          \
    acc[0] += blo((v).x); acc[1] += bhi((v).x);          \
    acc[2] += blo((v).y); acc[3] += bhi((v).y);          \
    acc[4] += blo((v).z); acc[5] += bhi((v).z);          \
    acc[6] += blo((v).w); acc[7] += bhi((v).w);

// ================= bucketed CSR build (unchanged) =================

__global__ __launch_bounds__(256) void hist_k(const int* __restrict__ ei,
                                              uint* __restrict__ hist, int E, int n) {
    __shared__ uint h[256];
    int t = threadIdx.x, blk = blockIdx.x;
    int nb = (n + 511) >> 9;
    h[t] = 0;
    __syncthreads();
    int chunk = (E + 255) / 256;
    int e0 = blk * chunk, e1 = min(E, e0 + chunk);
    for (int e = e0 + t; e < e1; e += 256)
        atomicAdd(&h[((uint)ei[(size_t)E + e]) >> 9], 1u);
    __syncthreads();
    if (t < nb) hist[(size_t)t * 256 + blk] = h[t];
}

__global__ __launch_bounds__(256) void scanA_k(const uint* __restrict__ hist,
                                               uint* __restrict__ histex,
                                               uint* __restrict__ btot) {
    __shared__ uint s[256];
    int t = threadIdx.x, b = blockIdx.x;
    uint v = hist[(size_t)b * 256 + t];
    s[t] = v;
    __syncthreads();
    for (int off = 1; off < 256; off <<= 1) {
        uint u = (t >= off) ? s[t - off] : 0;
        __syncthreads();
        s[t] += u;
        __syncthreads();
    }
    histex[(size_t)b * 256 + t] = s[t] - v;
    if (t == 255) btot[b] = s[255];
}

__global__ __launch_bounds__(256) void scanB_k(const uint* __restrict__ btot,
                                               uint* __restrict__ bbase,
                                               int* __restrict__ rp, int n, int E) {
    __shared__ uint s[256];
    int t = threadIdx.x;
    int nb = (n + 511) >> 9;
    uint v = (t < nb) ? btot[t] : 0;
    s[t] = v;
    __syncthreads();
    for (int off = 1; off < 256; off <<= 1) {
        uint u = (t >= off) ? s[t - off] : 0;
        __syncthreads();
        s[t] += u;
        __syncthreads();
    }
    if (t < nb) bbase[t] = s[t] - v;
    if (t == nb - 1) bbase[nb] = s[t];
    if (t == 0) rp[n] = E;
}

__global__ __launch_bounds__(256) void scat_k(const int* __restrict__ ei,
                                              const uint* __restrict__ bbase,
                                              const uint* __restrict__ histex,
                                              uint* __restrict__ pairs, int E, int n) {
    __shared__ uint cur[256];
    int t = threadIdx.x, blk = blockIdx.x;
    int nb = (n + 511) >> 9;
    if (t < nb) cur[t] = bbase[t] + histex[(size_t)t * 256 + blk];
    __syncthreads();
    int chunk = (E + 255) / 256;
    int e0 = blk * chunk, e1 = min(E, e0 + chunk);
    for (int e = e0 + t; e < e1; e += 256) {
        uint src = (uint)ei[e];
        uint dst = (uint)ei[(size_t)E + e];
        uint p = atomicAdd(&cur[dst >> 9], 1u);
        pairs[p] = (src << 9) | (dst & 511u);
    }
}

__global__ __launch_bounds__(256) void build_k(const uint* __restrict__ pairs,
                                               const uint* __restrict__ bbase,
                                               int* __restrict__ rp,
                                               float* __restrict__ dinv,
                                               int* __restrict__ eb, int n) {
    __shared__ uint lcnt[512];
    __shared__ uint lsc[256];
    int t = threadIdx.x, b = blockIdx.x;
    uint e0 = bbase[b], e1 = bbase[b + 1];
    lcnt[t] = 0;
    lcnt[t + 256] = 0;
    __syncthreads();
    for (uint e = e0 + t; e < e1; e += 256)
        atomicAdd(&lcnt[pairs[e] & 511u], 1u);
    __syncthreads();
    uint c0 = lcnt[2 * t], c1 = lcnt[2 * t + 1];
    uint sm = c0 + c1;
    lsc[t] = sm;
    __syncthreads();
    for (int off = 1; off < 256; off <<= 1) {
        uint u = (t >= off) ? lsc[t - off] : 0;
        __syncthreads();
        lsc[t] += u;
        __syncthreads();
    }
    uint ex = lsc[t] - sm;
    int node0 = (b << 9) + 2 * t;
    if (node0 < n) {
        rp[node0] = (int)(e0 + ex);
        dinv[node0] = rsqrtf((float)(c0 + 1));
    }
    if (node0 + 1 < n) {
        rp[node0 + 1] = (int)(e0 + ex + c0);
        dinv[node0 + 1] = rsqrtf((float)(c1 + 1));
    }
    lcnt[2 * t] = e0 + ex;
    lcnt[2 * t + 1] = e0 + ex + c0;
    __syncthreads();
    for (uint e = e0 + t; e < e1; e += 256) {
        uint p = pairs[e];
        uint pos = atomicAdd(&lcnt[p & 511u], 1u);
        eb[pos] = (int)(p >> 9);
    }
}

// ================= W pre-convert (unchanged) =================

__global__ __launch_bounds__(256) void wprep_k(const float* __restrict__ W,
                                               ushort* __restrict__ Wb, int OUTC) {
    int idx = blockIdx.x * 256 + threadIdx.x;
    if (idx >= OUTC * 128) return;
    int k = idx / OUTC, c = idx % OUTC;
    Wb[c * 128 + (k ^ ((c & 7) << 3))] = f2bu(W[idx]);
}

// ================= MFMA bf16 GEMM (unchanged) =================

template <int OUTC, bool INB>
__global__ __launch_bounds__(256) void mgemm_k(const void* __restrict__ Xv,
                                               const uint4* __restrict__ Wbv,
                                               const float* __restrict__ dinv,
                                               uint* __restrict__ outb, int n) {
    constexpr int WOFF = 32768;
    constexpr int C4 = OUTC / 4;
    constexpr int NC = OUTC / 16;
    constexpr int LDSB = (32768 + OUTC * 256) > (128 * OUTC * 4)
                             ? (32768 + OUTC * 256) : (128 * OUTC * 4);
    __shared__ uint4 ldsv[LDSB / 16];
    char* lds = (char*)ldsv;

    int t = threadIdx.x;
    int r0b = blockIdx.x * 128;

    for (int i = t; i < OUTC * 16; i += 256)
        ((uint4*)(lds + WOFF))[i] = Wbv[i];

    if constexpr (!INB) {
        for (int i = t; i < 128 * 32; i += 256) {
            int r = i >> 5, kq = i & 31;
            uint2 p = make_uint2(0u, 0u);
            if (r0b + r < n) {
                float di = dinv[r0b + r];
                float4 v = ((const float4*)Xv)[(size_t)(r0b + r) * 32 + kq];
                p = make_uint2(fpack2(v.x * di, v.y * di), fpack2(v.z * di, v.w * di));
            }
            *(uint2*)(lds + r * 256 + ((kq * 8) ^ ((r & 7) << 4))) = p;
        }
    } else {
        for (int i = t; i < 128 * 16; i += 256) {
            int r = i >> 4, kq = i & 15;
            uint4 p = make_uint4(0u, 0u, 0u, 0u);
            if (r0b + r < n)
                p = ((const uint4*)Xv)[((size_t)(kq >> 1) * n + (r0b + r)) * 2 + (kq & 1)];
            *(uint4*)(lds + r * 256 + ((kq * 16) ^ ((r & 7) << 4))) = p;
        }
    }
    __syncthreads();

    int wv = t >> 6, lane = t & 63;
    int l15 = lane & 15, lg = lane >> 4;
    int wr0 = wv * 32;
    int swz = (l15 & 7) << 4;

    f32x4 acc[2][NC];
#pragma unroll
    for (int r = 0; r < 2; ++r)
#pragma unroll
        for (int cj = 0; cj < NC; ++cj) acc[r][cj] = (f32x4){0.f, 0.f, 0.f, 0.f};

#pragma unroll
    for (int kk = 0; kk < 4; ++kk) {
        int koff = kk * 64 + lg * 16;
        bf16x8 a0 = *(bf16x8*)(lds + (wr0 + l15) * 256 + (koff ^ swz));
        bf16x8 a1 = *(bf16x8*)(lds + (wr0 + 16 + l15) * 256 + (koff ^ swz));
#pragma unroll
        for (int cj = 0; cj < NC; ++cj) {
            int c = cj * 16 + l15;
            bf16x8 bv = *(bf16x8*)(lds + WOFF + c * 256 + (koff ^ swz));
            acc[0][cj] = __builtin_amdgcn_mfma_f32_16x16x32_bf16(a0, bv, acc[0][cj], 0, 0, 0);
            acc[1][cj] = __builtin_amdgcn_mfma_f32_16x16x32_bf16(a1, bv, acc[1][cj], 0, 0, 0);
        }
    }
    __syncthreads();

#pragma unroll
    for (int r = 0; r < 2; ++r)
#pragma unroll
        for (int cj = 0; cj < NC; ++cj) {
            int row = wr0 + r * 16 + lg * 4;
            int col = cj * 16 + l15;
#pragma unroll
            for (int j = 0; j < 4; ++j)
                *(float*)(lds + ((size_t)(row + j) * OUTC + col) * 4) = acc[r][cj][j];
        }
    __syncthreads();

    for (int i = t; i < 128 * C4; i += 256) {
        int r = i / C4, c4 = (i % C4) * 4;
        if (r0b + r < n) {
            float4 d = *(float4*)(lds + (size_t)i * 16);
            uint2 p = make_uint2(fpack2(d.x, d.y), fpack2(d.z, d.w));
            ((uint2*)outb)[((size_t)(c4 >> 4) * n + (r0b + r)) * 4 + ((c4 >> 2) & 3)] = p;
        }
    }
}

// ================= Aggregation v12: 2 lanes/node, NO LDS staging =================
// eb read directly from global: per lane 32B-contiguous scalar dword stream,
// both lanes of a node read identical addresses (broadcast). Removes stage loop,
// barrier, LDS (occupancy cap) and all bank conflicts. Depth-8 gathers in flight.
// Group slices stay L2-resident; nt output stores.

template <int NPB>
__global__ __launch_bounds__(128) void agg128v_k(const uint4* __restrict__ hg,
                                                 const int* __restrict__ rp,
                                                 const int* __restrict__ eb,
                                                 const float* __restrict__ dinv,
                                                 const float* __restrict__ bias,
                                                 uint* __restrict__ a1g, int n) {
    int g = blockIdx.x & 7;
    int blkn = blockIdx.x >> 3;
    int t = threadIdx.x;
    int half = t & 1;
    const uint4* base = hg + (size_t)g * n * 2 + half;

    int d0 = blkn * NPB;
    int dend = min(n, d0 + NPB);
    int d = d0 + (t >> 1);
    bool valid = d < dend;
    int e = 0, e1 = 0;
    float acc[8];
#pragma unroll
    for (int j = 0; j < 8; ++j) acc[j] = 0.f;
    if (valid) {
        e = rp[d];
        e1 = rp[d + 1];
        uint4 s0 = base[(size_t)d * 2];
        ACC8(s0);
    }
    while (__any(e + 8 <= e1)) {
        if (e + 8 <= e1) {
            int s0 = eb[e], s1 = eb[e + 1], s2 = eb[e + 2], s3 = eb[e + 3];
            int s4 = eb[e + 4], s5 = eb[e + 5], s6 = eb[e + 6], s7 = eb[e + 7];
            uint4 v0 = base[(size_t)s0 * 2];
            uint4 v1 = base[(size_t)s1 * 2];
            uint4 v2 = base[(size_t)s2 * 2];
            uint4 v3 = base[(size_t)s3 * 2];
            uint4 v4 = base[(size_t)s4 * 2];
            uint4 v5 = base[(size_t)s5 * 2];
            uint4 v6 = base[(size_t)s6 * 2];
            uint4 v7 = base[(size_t)s7 * 2];
            ACC8(v0); ACC8(v1); ACC8(v2); ACC8(v3);
            ACC8(v4); ACC8(v5); ACC8(v6); ACC8(v7);
            e += 8;
        }
    }
    while (__any(e < e1)) {
        if (e < e1) {
            uint4 v = base[(size_t)eb[e] * 2];
            ACC8(v);
            ++e;
        }
    }
    if (valid) {
        float di = dinv[d];
        const float* bp = bias + g * 16 + half * 8;
        uint o[4];
#pragma unroll
        for (int j = 0; j < 4; ++j)
            o[j] = fpack2(fmaxf(acc[2 * j] * di + bp[2 * j], 0.f) * di,
                          fmaxf(acc[2 * j + 1] * di + bp[2 * j + 1], 0.f) * di);
        uintx4 p0 = {o[0], o[1], o[2], o[3]};
        uintx4* dst = (uintx4*)(a1g + ((size_t)g * n + d) * 8 + half * 4);
        __builtin_nontemporal_store(p0, dst);
    }
}

template <int NPB>
__global__ __launch_bounds__(128) void agg64v_k(const uint4* __restrict__ hg,
                                                const int* __restrict__ rp,
                                                const int* __restrict__ eb,
                                                const float* __restrict__ dinv,
                                                const float* __restrict__ bias,
                                                float* __restrict__ out, int n) {
    int g = blockIdx.x & 3;
    int blkn = blockIdx.x >> 2;
    int t = threadIdx.x;
    int half = t & 1;
    const uint4* base = hg + (size_t)g * n * 2 + half;

    int d0 = blkn * NPB;
    int dend = min(n, d0 + NPB);
    int d = d0 + (t >> 1);
    bool valid = d < dend;
    int e = 0, e1 = 0;
    float acc[8];
#pragma unroll
    for (int j = 0; j < 8; ++j) acc[j] = 0.f;
    if (valid) {
        e = rp[d];
        e1 = rp[d + 1];
        uint4 s0 = base[(size_t)d * 2];
        ACC8(s0);
    }
    while (__any(e + 8 <= e1)) {
        if (e + 8 <= e1) {
            int s0 = eb[e], s1 = eb[e + 1], s2 = eb[e + 2], s3 = eb[e + 3];
            int s4 = eb[e + 4], s5 = eb[e + 5], s6 = eb[e + 6], s7 = eb[e + 7];
            uint4 v0 = base[(size_t)s0 * 2];
            uint4 v1 = base[(size_t)s1 * 2];
            uint4 v2 = base[(size_t)s2 * 2];
            uint4 v3 = base[(size_t)s3 * 2];
            uint4 v4 = base[(size_t)s4 * 2];
            uint4 v5 = base[(size_t)s5 * 2];
            uint4 v6 = base[(size_t)s6 * 2];
            uint4 v7 = base[(size_t)s7 * 2];
            ACC8(v0); ACC8(v1); ACC8(v2); ACC8(v3);
            ACC8(v4); ACC8(v5); ACC8(v6); ACC8(v7);
            e += 8;
        }
    }
    while (__any(e < e1)) {
        if (e < e1) {
            uint4 v = base[(size_t)eb[e] * 2];
            ACC8(v);
            ++e;
        }
    }
    if (valid) {
        float di = dinv[d];
        const float* bp = bias + g * 16 + half * 8;
        float* op = out + (size_t)d * 64 + g * 16 + half * 8;
        floatx4 o0 = {acc[0] * di + bp[0], acc[1] * di + bp[1],
                      acc[2] * di + bp[2], acc[3] * di + bp[3]};
        floatx4 o1 = {acc[4] * di + bp[4], acc[5] * di + bp[5],
                      acc[6] * di + bp[6], acc[7] * di + bp[7]};
        __builtin_nontemporal_store(o0, (floatx4*)op);
        __builtin_nontemporal_store(o1, (floatx4*)(op + 4));
    }
}

// ================= launch =================

extern "C" void kernel_launch(void* const* d_in, const int* in_sizes, int n_in,
                              void* d_out, int out_size, void* d_ws, size_t ws_size,
                              hipStream_t stream) {
    const float* x  = (const float*)d_in[0];
    const int*   ei = (const int*)d_in[1];
    const float* W1 = (const float*)d_in[2];
    const float* b1 = (const float*)d_in[3];
    const float* W2 = (const float*)d_in[4];
    const float* b2 = (const float*)d_in[5];
    float* out = (float*)d_out;

    int n = in_sizes[0] / 128;
    int E = in_sizes[1] / 2;
    int nb = (n + 511) >> 9;

    char* ws = (char*)d_ws;
    size_t o = 0;
    auto alloc = [&](size_t bytes) {
        size_t r = o;
        o = (o + bytes + 255) & ~(size_t)255;
        return r;
    };
    uint*   hist   = (uint*)(ws + alloc((size_t)256 * 256 * 4));
    uint*   histex = (uint*)(ws + alloc((size_t)256 * 256 * 4));
    uint*   btot   = (uint*)(ws + alloc(256 * 4));
    uint*   bbase  = (uint*)(ws + alloc(257 * 4));
    int*    rp     = (int*)(ws + alloc((size_t)(n + 1) * 4));
    float*  dinv   = (float*)(ws + alloc((size_t)n * 4));
    uint*   pairs  = (uint*)(ws + alloc((size_t)E * 4));
    int*    eb     = (int*)(ws + alloc((size_t)E * 4));
    ushort* W1b    = (ushort*)(ws + alloc((size_t)128 * 128 * 2));
    ushort* W2b    = (ushort*)(ws + alloc((size_t)64 * 128 * 2));
    uint*   h1g    = (uint*)(ws + alloc((size_t)n * 64 * 4));   // group-major [8][n][32B]
    uint*   a1g    = (uint*)(ws + alloc((size_t)n * 64 * 4));   // group-major [8][n][32B]
    uint*   h2g    = (uint*)(ws + alloc((size_t)n * 32 * 4));   // group-major [4][n][32B]

    int gB = (n + 127) / 128;
    constexpr int NPB = 64;       // nodes per block (128 thr, 2 lanes/node)
    int nch = (n + NPB - 1) / NPB;

    hist_k<<<256, 256, 0, stream>>>(ei, hist, E, n);
    scanA_k<<<nb, 256, 0, stream>>>(hist, histex, btot);
    scanB_k<<<1, 256, 0, stream>>>(btot, bbase, rp, n, E);
    scat_k<<<256, 256, 0, stream>>>(ei, bbase, histex, pairs, E, n);
    build_k<<<nb, 256, 0, stream>>>(pairs, bbase, rp, dinv, eb, n);
    wprep_k<<<(128 * 128 + 255) / 256, 256, 0, stream>>>(W1, W1b, 128);
    wprep_k<<<(64 * 128 + 255) / 256, 256, 0, stream>>>(W2, W2b, 64);

    // layer 1
    mgemm_k<128, false><<<gB, 256, 0, stream>>>(x, (const uint4*)W1b, dinv, h1g, n);
    agg128v_k<NPB><<<8 * nch, 128, 0, stream>>>((const uint4*)h1g, rp, eb, dinv,
                                                b1, a1g, n);
    // layer 2
    mgemm_k<64, true><<<gB, 256, 0, stream>>>(a1g, (const uint4*)W2b, dinv, h2g, n);
    agg64v_k<NPB><<<4 * nch, 128, 0, stream>>>((const uint4*)h2g, rp, eb, dinv,
                                               b2, out, n);
}

// Round 18
// 208.162 us; speedup vs baseline: 1.1107x; 1.1107x over previous
//
#include <hip/hip_runtime.h>
#include <hip/hip_bf16.h>
#include <cstdint>

typedef short bf16x8 __attribute__((ext_vector_type(8)));
typedef float f32x4 __attribute__((ext_vector_type(4)));
typedef uint uintx4 __attribute__((ext_vector_type(4)));
typedef float floatx4 __attribute__((ext_vector_type(4)));

// ---------------- bf16 helpers ----------------

__device__ inline float blo(uint u) { return __uint_as_float(u << 16); }
__device__ inline float bhi(uint u) { return __uint_as_float(u & 0xffff0000u); }
__device__ inline ushort f2bu(float x) {
    __hip_bfloat16 h = __float2bfloat16(x);
    return *reinterpret_cast<ushort*>(&h);
}
__device__ inline uint fpack2(float x, float y) {
    return (uint)f2bu(x) | ((uint)f2bu(y) << 16);
}

// 8 channels from one uint4 into acc[0..7]
#define ACC8(v)                                          \
    acc[0] += blo((v).x); acc[1] += bhi((v).x);          \
    acc[2] += blo((v).y); acc[3] += bhi((v).y);          \
    acc[4] += blo((v).z); acc[5] += bhi((v).z);          \
    acc[6] += blo((v).w); acc[7] += bhi((v).w);

// ================= bucketed CSR build (unchanged) =================

__global__ __launch_bounds__(256) void hist_k(const int* __restrict__ ei,
                                              uint* __restrict__ hist, int E, int n) {
    __shared__ uint h[256];
    int t = threadIdx.x, blk = blockIdx.x;
    int nb = (n + 511) >> 9;
    h[t] = 0;
    __syncthreads();
    int chunk = (E + 255) / 256;
    int e0 = blk * chunk, e1 = min(E, e0 + chunk);
    for (int e = e0 + t; e < e1; e += 256)
        atomicAdd(&h[((uint)ei[(size_t)E + e]) >> 9], 1u);
    __syncthreads();
    if (t < nb) hist[(size_t)t * 256 + blk] = h[t];
}

__global__ __launch_bounds__(256) void scanA_k(const uint* __restrict__ hist,
                                               uint* __restrict__ histex,
                                               uint* __restrict__ btot) {
    __shared__ uint s[256];
    int t = threadIdx.x, b = blockIdx.x;
    uint v = hist[(size_t)b * 256 + t];
    s[t] = v;
    __syncthreads();
    for (int off = 1; off < 256; off <<= 1) {
        uint u = (t >= off) ? s[t - off] : 0;
        __syncthreads();
        s[t] += u;
        __syncthreads();
    }
    histex[(size_t)b * 256 + t] = s[t] - v;
    if (t == 255) btot[b] = s[255];
}

__global__ __launch_bounds__(256) void scanB_k(const uint* __restrict__ btot,
                                               uint* __restrict__ bbase,
                                               int* __restrict__ rp, int n, int E) {
    __shared__ uint s[256];
    int t = threadIdx.x;
    int nb = (n + 511) >> 9;
    uint v = (t < nb) ? btot[t] : 0;
    s[t] = v;
    __syncthreads();
    for (int off = 1; off < 256; off <<= 1) {
        uint u = (t >= off) ? s[t - off] : 0;
        __syncthreads();
        s[t] += u;
        __syncthreads();
    }
    if (t < nb) bbase[t] = s[t] - v;
    if (t == nb - 1) bbase[nb] = s[t];
    if (t == 0) rp[n] = E;
}

__global__ __launch_bounds__(256) void scat_k(const int* __restrict__ ei,
                                              const uint* __restrict__ bbase,
                                              const uint* __restrict__ histex,
                                              uint* __restrict__ pairs, int E, int n) {
    __shared__ uint cur[256];
    int t = threadIdx.x, blk = blockIdx.x;
    int nb = (n + 511) >> 9;
    if (t < nb) cur[t] = bbase[t] + histex[(size_t)t * 256 + blk];
    __syncthreads();
    int chunk = (E + 255) / 256;
    int e0 = blk * chunk, e1 = min(E, e0 + chunk);
    for (int e = e0 + t; e < e1; e += 256) {
        uint src = (uint)ei[e];
        uint dst = (uint)ei[(size_t)E + e];
        uint p = atomicAdd(&cur[dst >> 9], 1u);
        pairs[p] = (src << 9) | (dst & 511u);
    }
}

__global__ __launch_bounds__(256) void build_k(const uint* __restrict__ pairs,
                                               const uint* __restrict__ bbase,
                                               int* __restrict__ rp,
                                               float* __restrict__ dinv,
                                               int* __restrict__ eb, int n) {
    __shared__ uint lcnt[512];
    __shared__ uint lsc[256];
    int t = threadIdx.x, b = blockIdx.x;
    uint e0 = bbase[b], e1 = bbase[b + 1];
    lcnt[t] = 0;
    lcnt[t + 256] = 0;
    __syncthreads();
    for (uint e = e0 + t; e < e1; e += 256)
        atomicAdd(&lcnt[pairs[e] & 511u], 1u);
    __syncthreads();
    uint c0 = lcnt[2 * t], c1 = lcnt[2 * t + 1];
    uint sm = c0 + c1;
    lsc[t] = sm;
    __syncthreads();
    for (int off = 1; off < 256; off <<= 1) {
        uint u = (t >= off) ? lsc[t - off] : 0;
        __syncthreads();
        lsc[t] += u;
        __syncthreads();
    }
    uint ex = lsc[t] - sm;
    int node0 = (b << 9) + 2 * t;
    if (node0 < n) {
        rp[node0] = (int)(e0 + ex);
        dinv[node0] = rsqrtf((float)(c0 + 1));
    }
    if (node0 + 1 < n) {
        rp[node0 + 1] = (int)(e0 + ex + c0);
        dinv[node0 + 1] = rsqrtf((float)(c1 + 1));
    }
    lcnt[2 * t] = e0 + ex;
    lcnt[2 * t + 1] = e0 + ex + c0;
    __syncthreads();
    for (uint e = e0 + t; e < e1; e += 256) {
        uint p = pairs[e];
        uint pos = atomicAdd(&lcnt[p & 511u], 1u);
        eb[pos] = (int)(p >> 9);
    }
}

// ================= W pre-convert: both weights in one launch =================

__global__ __launch_bounds__(256) void wprep2_k(const float* __restrict__ W1,
                                                ushort* __restrict__ W1b,
                                                const float* __restrict__ W2,
                                                ushort* __restrict__ W2b) {
    int idx = blockIdx.x * 256 + threadIdx.x;
    if (idx < 128 * 128) {
        int k = idx / 128, c = idx % 128;
        W1b[c * 128 + (k ^ ((c & 7) << 3))] = f2bu(W1[idx]);
    } else if (idx < 128 * 128 + 64 * 128) {
        int j = idx - 128 * 128;
        int k = j / 64, c = j % 64;
        W2b[c * 128 + (k ^ ((c & 7) << 3))] = f2bu(W2[j]);
    }
}

// ================= MFMA bf16 GEMM (unchanged) =================

template <int OUTC, bool INB>
__global__ __launch_bounds__(256) void mgemm_k(const void* __restrict__ Xv,
                                               const uint4* __restrict__ Wbv,
                                               const float* __restrict__ dinv,
                                               uint* __restrict__ outb, int n) {
    constexpr int WOFF = 32768;
    constexpr int C4 = OUTC / 4;
    constexpr int NC = OUTC / 16;
    constexpr int LDSB = (32768 + OUTC * 256) > (128 * OUTC * 4)
                             ? (32768 + OUTC * 256) : (128 * OUTC * 4);
    __shared__ uint4 ldsv[LDSB / 16];
    char* lds = (char*)ldsv;

    int t = threadIdx.x;
    int r0b = blockIdx.x * 128;

    for (int i = t; i < OUTC * 16; i += 256)
        ((uint4*)(lds + WOFF))[i] = Wbv[i];

    if constexpr (!INB) {
        for (int i = t; i < 128 * 32; i += 256) {
            int r = i >> 5, kq = i & 31;
            uint2 p = make_uint2(0u, 0u);
            if (r0b + r < n) {
                float di = dinv[r0b + r];
                float4 v = ((const float4*)Xv)[(size_t)(r0b + r) * 32 + kq];
                p = make_uint2(fpack2(v.x * di, v.y * di), fpack2(v.z * di, v.w * di));
            }
            *(uint2*)(lds + r * 256 + ((kq * 8) ^ ((r & 7) << 4))) = p;
        }
    } else {
        for (int i = t; i < 128 * 16; i += 256) {
            int r = i >> 4, kq = i & 15;
            uint4 p = make_uint4(0u, 0u, 0u, 0u);
            if (r0b + r < n)
                p = ((const uint4*)Xv)[((size_t)(kq >> 1) * n + (r0b + r)) * 2 + (kq & 1)];
            *(uint4*)(lds + r * 256 + ((kq * 16) ^ ((r & 7) << 4))) = p;
        }
    }
    __syncthreads();

    int wv = t >> 6, lane = t & 63;
    int l15 = lane & 15, lg = lane >> 4;
    int wr0 = wv * 32;
    int swz = (l15 & 7) << 4;

    f32x4 acc[2][NC];
#pragma unroll
    for (int r = 0; r < 2; ++r)
#pragma unroll
        for (int cj = 0; cj < NC; ++cj) acc[r][cj] = (f32x4){0.f, 0.f, 0.f, 0.f};

#pragma unroll
    for (int kk = 0; kk < 4; ++kk) {
        int koff = kk * 64 + lg * 16;
        bf16x8 a0 = *(bf16x8*)(lds + (wr0 + l15) * 256 + (koff ^ swz));
        bf16x8 a1 = *(bf16x8*)(lds + (wr0 + 16 + l15) * 256 + (koff ^ swz));
#pragma unroll
        for (int cj = 0; cj < NC; ++cj) {
            int c = cj * 16 + l15;
            bf16x8 bv = *(bf16x8*)(lds + WOFF + c * 256 + (koff ^ swz));
            acc[0][cj] = __builtin_amdgcn_mfma_f32_16x16x32_bf16(a0, bv, acc[0][cj], 0, 0, 0);
            acc[1][cj] = __builtin_amdgcn_mfma_f32_16x16x32_bf16(a1, bv, acc[1][cj], 0, 0, 0);
        }
    }
    __syncthreads();

#pragma unroll
    for (int r = 0; r < 2; ++r)
#pragma unroll
        for (int cj = 0; cj < NC; ++cj) {
            int row = wr0 + r * 16 + lg * 4;
            int col = cj * 16 + l15;
#pragma unroll
            for (int j = 0; j < 4; ++j)
                *(float*)(lds + ((size_t)(row + j) * OUTC + col) * 4) = acc[r][cj][j];
        }
    __syncthreads();

    for (int i = t; i < 128 * C4; i += 256) {
        int r = i / C4, c4 = (i % C4) * 4;
        if (r0b + r < n) {
            float4 d = *(float4*)(lds + (size_t)i * 16);
            uint2 p = make_uint2(fpack2(d.x, d.y), fpack2(d.z, d.w));
            ((uint2*)outb)[((size_t)(c4 >> 4) * n + (r0b + r)) * 4 + ((c4 >> 2) & 3)] = p;
        }
    }
}

// ================= Aggregation v11 (r16 best): 2 lanes/node, LDS eb, depth-8 =================

template <int NPB, int EBCAP>
__global__ __launch_bounds__(128) void agg128v_k(const uint4* __restrict__ hg,
                                                 const int* __restrict__ rp,
                                                 const int* __restrict__ eb,
                                                 const float* __restrict__ dinv,
                                                 const float* __restrict__ bias,
                                                 uint* __restrict__ a1g, int n) {
    __shared__ int ebs[EBCAP];
    int g = blockIdx.x & 7;
    int blkn = blockIdx.x >> 3;
    int t = threadIdx.x;
    int half = t & 1;
    const uint4* base = hg + (size_t)g * n * 2 + half;

    int d0 = blkn * NPB;
    int dend = min(n, d0 + NPB);
    int es = rp[d0], ee = rp[dend];
    int cnt = ee - es;
    int scnt = min(cnt, EBCAP);
    for (int i = t; i < scnt; i += 128) ebs[i] = eb[es + i];
    __syncthreads();

    int d = d0 + (t >> 1);
    bool valid = d < dend;
    int e = 0, e1 = 0;
    float acc[8];
#pragma unroll
    for (int j = 0; j < 8; ++j) acc[j] = 0.f;
    if (valid) {
        e = rp[d] - es;
        e1 = rp[d + 1] - es;
        uint4 s0 = base[(size_t)d * 2];
        ACC8(s0);
    }
    if (cnt <= EBCAP) {
        while (__any(e + 8 <= e1)) {
            if (e + 8 <= e1) {
                int s0 = ebs[e], s1 = ebs[e + 1], s2 = ebs[e + 2], s3 = ebs[e + 3];
                int s4 = ebs[e + 4], s5 = ebs[e + 5], s6 = ebs[e + 6], s7 = ebs[e + 7];
                uint4 v0 = base[(size_t)s0 * 2];
                uint4 v1 = base[(size_t)s1 * 2];
                uint4 v2 = base[(size_t)s2 * 2];
                uint4 v3 = base[(size_t)s3 * 2];
                uint4 v4 = base[(size_t)s4 * 2];
                uint4 v5 = base[(size_t)s5 * 2];
                uint4 v6 = base[(size_t)s6 * 2];
                uint4 v7 = base[(size_t)s7 * 2];
                ACC8(v0); ACC8(v1); ACC8(v2); ACC8(v3);
                ACC8(v4); ACC8(v5); ACC8(v6); ACC8(v7);
                e += 8;
            }
        }
        while (__any(e < e1)) {
            if (e < e1) {
                uint4 v = base[(size_t)ebs[e] * 2];
                ACC8(v);
                ++e;
            }
        }
    } else {
        const int* ebg = eb + es;
        while (__any(e + 8 <= e1)) {
            if (e + 8 <= e1) {
                int s0 = ebg[e], s1 = ebg[e + 1], s2 = ebg[e + 2], s3 = ebg[e + 3];
                int s4 = ebg[e + 4], s5 = ebg[e + 5], s6 = ebg[e + 6], s7 = ebg[e + 7];
                uint4 v0 = base[(size_t)s0 * 2];
                uint4 v1 = base[(size_t)s1 * 2];
                uint4 v2 = base[(size_t)s2 * 2];
                uint4 v3 = base[(size_t)s3 * 2];
                uint4 v4 = base[(size_t)s4 * 2];
                uint4 v5 = base[(size_t)s5 * 2];
                uint4 v6 = base[(size_t)s6 * 2];
                uint4 v7 = base[(size_t)s7 * 2];
                ACC8(v0); ACC8(v1); ACC8(v2); ACC8(v3);
                ACC8(v4); ACC8(v5); ACC8(v6); ACC8(v7);
                e += 8;
            }
        }
        while (__any(e < e1)) {
            if (e < e1) {
                uint4 v = base[(size_t)ebg[e] * 2];
                ACC8(v);
                ++e;
            }
        }
    }
    if (valid) {
        float di = dinv[d];
        const float* bp = bias + g * 16 + half * 8;
        uint o[4];
#pragma unroll
        for (int j = 0; j < 4; ++j)
            o[j] = fpack2(fmaxf(acc[2 * j] * di + bp[2 * j], 0.f) * di,
                          fmaxf(acc[2 * j + 1] * di + bp[2 * j + 1], 0.f) * di);
        uintx4 p0 = {o[0], o[1], o[2], o[3]};
        uintx4* dst = (uintx4*)(a1g + ((size_t)g * n + d) * 8 + half * 4);
        __builtin_nontemporal_store(p0, dst);
    }
}

template <int NPB, int EBCAP>
__global__ __launch_bounds__(128) void agg64v_k(const uint4* __restrict__ hg,
                                                const int* __restrict__ rp,
                                                const int* __restrict__ eb,
                                                const float* __restrict__ dinv,
                                                const float* __restrict__ bias,
                                                float* __restrict__ out, int n) {
    __shared__ int ebs[EBCAP];
    int g = blockIdx.x & 3;
    int blkn = blockIdx.x >> 2;
    int t = threadIdx.x;
    int half = t & 1;
    const uint4* base = hg + (size_t)g * n * 2 + half;

    int d0 = blkn * NPB;
    int dend = min(n, d0 + NPB);
    int es = rp[d0], ee = rp[dend];
    int cnt = ee - es;
    int scnt = min(cnt, EBCAP);
    for (int i = t; i < scnt; i += 128) ebs[i] = eb[es + i];
    __syncthreads();

    int d = d0 + (t >> 1);
    bool valid = d < dend;
    int e = 0, e1 = 0;
    float acc[8];
#pragma unroll
    for (int j = 0; j < 8; ++j) acc[j] = 0.f;
    if (valid) {
        e = rp[d] - es;
        e1 = rp[d + 1] - es;
        uint4 s0 = base[(size_t)d * 2];
        ACC8(s0);
    }
    if (cnt <= EBCAP) {
        while (__any(e + 8 <= e1)) {
            if (e + 8 <= e1) {
                int s0 = ebs[e], s1 = ebs[e + 1], s2 = ebs[e + 2], s3 = ebs[e + 3];
                int s4 = ebs[e + 4], s5 = ebs[e + 5], s6 = ebs[e + 6], s7 = ebs[e + 7];
                uint4 v0 = base[(size_t)s0 * 2];
                uint4 v1 = base[(size_t)s1 * 2];
                uint4 v2 = base[(size_t)s2 * 2];
                uint4 v3 = base[(size_t)s3 * 2];
                uint4 v4 = base[(size_t)s4 * 2];
                uint4 v5 = base[(size_t)s5 * 2];
                uint4 v6 = base[(size_t)s6 * 2];
                uint4 v7 = base[(size_t)s7 * 2];
                ACC8(v0); ACC8(v1); ACC8(v2); ACC8(v3);
                ACC8(v4); ACC8(v5); ACC8(v6); ACC8(v7);
                e += 8;
            }
        }
        while (__any(e < e1)) {
            if (e < e1) {
                uint4 v = base[(size_t)ebs[e] * 2];
                ACC8(v);
                ++e;
            }
        }
    } else {
        const int* ebg = eb + es;
        while (__any(e < e1)) {
            if (e < e1) {
                uint4 v = base[(size_t)ebg[e] * 2];
                ACC8(v);
                ++e;
            }
        }
    }
    if (valid) {
        float di = dinv[d];
        const float* bp = bias + g * 16 + half * 8;
        float* op = out + (size_t)d * 64 + g * 16 + half * 8;
        floatx4 o0 = {acc[0] * di + bp[0], acc[1] * di + bp[1],
                      acc[2] * di + bp[2], acc[3] * di + bp[3]};
        floatx4 o1 = {acc[4] * di + bp[4], acc[5] * di + bp[5],
                      acc[6] * di + bp[6], acc[7] * di + bp[7]};
        __builtin_nontemporal_store(o0, (floatx4*)op);
        __builtin_nontemporal_store(o1, (floatx4*)(op + 4));
    }
}

// ================= launch =================

extern "C" void kernel_launch(void* const* d_in, const int* in_sizes, int n_in,
                              void* d_out, int out_size, void* d_ws, size_t ws_size,
                              hipStream_t stream) {
    const float* x  = (const float*)d_in[0];
    const int*   ei = (const int*)d_in[1];
    const float* W1 = (const float*)d_in[2];
    const float* b1 = (const float*)d_in[3];
    const float* W2 = (const float*)d_in[4];
    const float* b2 = (const float*)d_in[5];
    float* out = (float*)d_out;

    int n = in_sizes[0] / 128;
    int E = in_sizes[1] / 2;
    int nb = (n + 511) >> 9;

    char* ws = (char*)d_ws;
    size_t o = 0;
    auto alloc = [&](size_t bytes) {
        size_t r = o;
        o = (o + bytes + 255) & ~(size_t)255;
        return r;
    };
    uint*   hist   = (uint*)(ws + alloc((size_t)256 * 256 * 4));
    uint*   histex = (uint*)(ws + alloc((size_t)256 * 256 * 4));
    uint*   btot   = (uint*)(ws + alloc(256 * 4));
    uint*   bbase  = (uint*)(ws + alloc(257 * 4));
    int*    rp     = (int*)(ws + alloc((size_t)(n + 1) * 4));
    float*  dinv   = (float*)(ws + alloc((size_t)n * 4));
    uint*   pairs  = (uint*)(ws + alloc((size_t)E * 4));
    int*    eb     = (int*)(ws + alloc((size_t)E * 4));
    ushort* W1b    = (ushort*)(ws + alloc((size_t)128 * 128 * 2));
    ushort* W2b    = (ushort*)(ws + alloc((size_t)64 * 128 * 2));
    uint*   h1g    = (uint*)(ws + alloc((size_t)n * 64 * 4));   // group-major [8][n][32B]
    uint*   a1g    = (uint*)(ws + alloc((size_t)n * 64 * 4));   // group-major [8][n][32B]
    uint*   h2g    = (uint*)(ws + alloc((size_t)n * 32 * 4));   // group-major [4][n][32B]

    int gB = (n + 127) / 128;
    constexpr int NPB = 64;       // nodes per block (128 thr, 2 lanes/node)
    constexpr int EBCAP = 1536;   // 6 KB LDS
    int nch = (n + NPB - 1) / NPB;

    hist_k<<<256, 256, 0, stream>>>(ei, hist, E, n);
    scanA_k<<<nb, 256, 0, stream>>>(hist, histex, btot);
    scanB_k<<<1, 256, 0, stream>>>(btot, bbase, rp, n, E);
    scat_k<<<256, 256, 0, stream>>>(ei, bbase, histex, pairs, E, n);
    build_k<<<nb, 256, 0, stream>>>(pairs, bbase, rp, dinv, eb, n);
    wprep2_k<<<(128 * 128 + 64 * 128 + 255) / 256, 256, 0, stream>>>(W1, W1b, W2, W2b);

    // layer 1
    mgemm_k<128, false><<<gB, 256, 0, stream>>>(x, (const uint4*)W1b, dinv, h1g, n);
    agg128v_k<NPB, EBCAP><<<8 * nch, 128, 0, stream>>>((const uint4*)h1g, rp, eb, dinv,
                                                       b1, a1g, n);
    // layer 2
    mgemm_k<64, true><<<gB, 256, 0, stream>>>(a1g, (const uint4*)W2b, dinv, h2g, n);
    agg64v_k<NPB, EBCAP><<<4 * nch, 128, 0, stream>>>((const uint4*)h2g, rp, eb, dinv,
                                                      b2, out, n);
}